// Round 7
// baseline (427.618 us; speedup 1.0000x reference)
//
#include <hip/hip_runtime.h>

typedef __bf16    bf16x8 __attribute__((ext_vector_type(8)));
typedef __bf16    bf16x4 __attribute__((ext_vector_type(4)));
typedef float     f32x4  __attribute__((ext_vector_type(4)));

#define BM 128
#define BN 128
#define BK 64
#define NBLK 512   // 2 blocks/CU x 256 CU; __launch_bounds__(256,2) guarantees fit

// async global->LDS, 16B per lane. LDS dest must be wave-uniform base + lane*16.
__device__ __forceinline__ void gload_lds16(const __bf16* g, __bf16* l) {
  __builtin_amdgcn_global_load_lds(
      (const __attribute__((address_space(1))) void*)g,
      (__attribute__((address_space(3))) void*)l,
      16, 0, 0);
}

// ============================================================================
// Explicit device-scope grid barrier (replaces cg::grid.sync(), which failed
// nondeterministically in round 6 — cross-XCD visibility not verifiable).
// Protocol per Guideline 16:
//  release: __syncthreads (each wave drains its stores, vmcnt=0) then
//           __threadfence (agent fence -> L2 writeback+invalidate on gfx950),
//           then device-scope atomic arrive;
//  spin:    atomicAdd(bar,0) RMW — served at the coherent point, cannot spin
//           on a stale cached value;
//  acquire: __threadfence, then __syncthreads releases the block.
// bar is memset to 0 by kernel_launch before every launch (graph-replay safe);
// targets are monotonic (512/1024/1536) so no in-kernel reset is needed.
// ============================================================================
__device__ __forceinline__ void grid_barrier(unsigned* bar, unsigned target) {
  __syncthreads();
  if (threadIdx.x == 0) {
    __threadfence();
    atomicAdd(bar, 1u);
    while (atomicAdd(bar, 0u) < target)
      __builtin_amdgcn_s_sleep(2);
    __threadfence();
  }
  __syncthreads();
}

// ============================================================================
// PROVEN inner structure (round 0/5; 16x16x32, 0 bank conflicts, ~730 TF).
// Round-4 NOTE: the 32x32x16 variant of this exact layout produced 4.19M
// conflict-cycles — mechanism unresolved; do NOT switch MFMA shape without
// re-measuring conflicts.
// LDS tiles: 16B slot g' of row r holds global k-group (g' ^ (r&7)), swizzle
// applied on the GLOBAL SOURCE address (gload_lds dest must stay linear).
// ============================================================================
__device__ __forceinline__ void gemm_core(
    const __bf16* A, const __bf16* B,
    int lda, int ldb, int K, int bm0, int bn0,
    int tid, int wm, int wn, int quad, int l15,
    __bf16* As, __bf16* Bs, f32x4 (&acc)[4][4])
{
  const __bf16* Ag[4];
  const __bf16* Bg[4];
#pragma unroll
  for (int c = 0; c < 4; ++c) {
    const int r  = c * 32 + (tid >> 3);
    const int g  = (tid & 7) ^ (r & 7);
    Ag[c] = A + (size_t)(bm0 + r) * lda + g * 8;
    Bg[c] = B + (size_t)(bn0 + r) * ldb + g * 8;
  }

  for (int k0 = 0; k0 < K; k0 += BK) {
#pragma unroll
    for (int c = 0; c < 4; ++c) {
      gload_lds16(Ag[c] + k0, &As[c * 2048 + tid * 8]);
      gload_lds16(Bg[c] + k0, &Bs[c * 2048 + tid * 8]);
    }
    __syncthreads();

#pragma unroll
    for (int kk = 0; kk < 2; ++kk) {
      bf16x8 af[4], bfv[4];
#pragma unroll
      for (int i = 0; i < 4; ++i) {
        const int R = wm + i * 16 + l15;
        af[i] = *(const bf16x8*)&As[R * BK + (((kk * 4 + quad) ^ (R & 7)) * 8)];
      }
#pragma unroll
      for (int i = 0; i < 4; ++i) {
        const int R = wn + i * 16 + l15;
        bfv[i] = *(const bf16x8*)&Bs[R * BK + (((kk * 4 + quad) ^ (R & 7)) * 8)];
      }
#pragma unroll
      for (int mi = 0; mi < 4; ++mi)
#pragma unroll
        for (int ni = 0; ni < 4; ++ni)
          acc[mi][ni] = __builtin_amdgcn_mfma_f32_16x16x32_bf16(
              af[mi], bfv[ni], acc[mi][ni], 0, 0, 0);
    }
    __syncthreads();
  }
}

// ============================================================================
// ROUND 7: persistent fused kernel, NORMAL launch + explicit grid barrier.
// Round-5 analysis: dispatch sum ~166us vs total ~245us -> ~79us in launch
// boundaries. Phase bodies are verbatim the round-5 verified kernels.
//   phase 0: fp32->bf16 cvt of x, Wq|Wk, Wv                   (grid-stride)
//   phase 1: proj — QK tiles [0,1024) + VT tiles [1024,1536)  (3 tiles/blk)
//   phase 2: scores — exp(QK^T/32)->Sc bf16 + row sums        (2 tiles/blk)
//   phase 3: PV — Sc@Vt^T * 1/lsum -> out fp32                (1 tile/blk)
// Stale-L1 audit: all cross-phase tensor reads go through global_load_lds
// (L2 path); lsum is never read before phase 3 -> no stale L1 lines possible.
// Sc aliases xb/Wqk/Wvb (consumed by end of phase 1; no __restrict__).
// ============================================================================
__global__ __launch_bounds__(256, 2)
void fused_attn(const float* __restrict__ x,  const float* __restrict__ Wq,
                const float* __restrict__ bq, const float* __restrict__ Wk,
                const float* __restrict__ bk, const float* __restrict__ Wv,
                const float* __restrict__ bv, float* out,
                __bf16* Q, __bf16* Kb, __bf16* Vt,
                __bf16* xb, __bf16* Wqk, __bf16* Wvb,
                __bf16* Sc, float* lsum, unsigned* bar)
{
  const int tid  = threadIdx.x;
  const int wave = tid >> 6;
  const int lane = tid & 63;
  const int quad = lane >> 4;
  const int l15  = lane & 15;
  const int wm   = (wave >> 1) * 64;
  const int wn   = (wave & 1) * 64;

  __shared__ __align__(16) __bf16 As[BM * BK];   // 16 KB
  __shared__ __align__(16) __bf16 Bs[BN * BK];   // 16 KB

  // ---------------- phase 0: cvt (grid-stride; lsum zeroed by host memset) --
  {
    const int g = blockIdx.x * 256 + tid;
    const int gs = NBLK * 256;
    for (int i = g; i < 2097152; i += gs) {          // x: 2^21 float4
      float4 v = ((const float4*)x)[i];
      bf16x4 o;
      o[0] = (__bf16)v.x; o[1] = (__bf16)v.y; o[2] = (__bf16)v.z; o[3] = (__bf16)v.w;
      ((bf16x4*)xb)[i] = o;
    }
    for (int i = g; i < 786432; i += gs) {           // 3 x 2^18 float4 weights
      const int mat = i >> 18;
      const int j   = i & 262143;
      const float* src = (mat == 0) ? Wq : (mat == 1) ? Wk : Wv;
      __bf16* dst = (mat == 0) ? Wqk : (mat == 1) ? (Wqk + 1048576) : Wvb;
      float4 v = ((const float4*)src)[j];
      bf16x4 o;
      o[0] = (__bf16)v.x; o[1] = (__bf16)v.y; o[2] = (__bf16)v.z; o[3] = (__bf16)v.w;
      ((bf16x4*)dst)[j] = o;
    }
  }
  grid_barrier(bar, NBLK);

  // ---------------- phase 1: proj (QK tiles 0..1023, VT tiles 1024..1535) --
  for (int t = blockIdx.x; t < 1536; t += NBLK) {
    const bool isQK = t < 1024;
    const __bf16* A;
    const __bf16* B;
    int bm0, bn0;
    if (isQK) {                       // 64 (M) x 16 (N)
      A = xb;  B = Wqk;
      bm0 = (t & 63) * BM;  bn0 = (t >> 6) * BN;
    } else {                          // 8 (M) x 64 (N)
      const int b2 = t - 1024;
      A = Wvb; B = xb;
      bm0 = (b2 & 7) * BM;  bn0 = (b2 >> 3) * BN;
    }

    f32x4 acc[4][4];
#pragma unroll
    for (int i = 0; i < 4; ++i)
#pragma unroll
      for (int j = 0; j < 4; ++j)
        acc[i][j] = (f32x4){0.f, 0.f, 0.f, 0.f};

    gemm_core(A, B, 1024, 1024, 1024, bm0, bn0, tid, wm, wn, quad, l15,
              As, Bs, acc);

    // C/D layout (verified m89/m91): row m = quad*4+r, col n = lane&15.
    if (isQK) {
#pragma unroll
      for (int mi = 0; mi < 4; ++mi) {
#pragma unroll
        for (int ni = 0; ni < 4; ++ni) {
          const int gn  = bn0 + wn + ni * 16 + l15;
          const int mat = gn >> 10;          // uniform per tile
          const int d   = gn & 1023;
          const float* bias = (mat == 0) ? bq : bk;
          __bf16* dst = (mat == 0) ? Q : Kb;
          const float bvv = bias[d];
#pragma unroll
          for (int r = 0; r < 4; ++r) {
            const int gm = bm0 + wm + mi * 16 + quad * 4 + r;
            dst[(size_t)gm * 1024 + d] = (__bf16)(acc[mi][ni][r] + bvv);
          }
        }
      }
    } else {  // VT: out Vt[b][gm][s], gn = b*2048 + s, bias bv[gm]
#pragma unroll
      for (int mi = 0; mi < 4; ++mi) {
#pragma unroll
        for (int ni = 0; ni < 4; ++ni) {
          const int gn = bn0 + wn + ni * 16 + l15;
          const int b  = gn >> 11, s = gn & 2047;
#pragma unroll
          for (int r = 0; r < 4; ++r) {
            const int gm = bm0 + wm + mi * 16 + quad * 4 + r;
            Vt[(size_t)b * (1024 * 2048) + (size_t)gm * 2048 + s] =
                (__bf16)(acc[mi][ni][r] + bv[gm]);
          }
        }
      }
    }
  }
  grid_barrier(bar, 2 * NBLK);

  // ---------------- phase 2: scores (16 x 16 x 4 batches = 1024 tiles) -----
  for (int t = blockIdx.x; t < 1024; t += NBLK) {
    const int bm0 = (t & 15) * BM;
    const int bn0 = ((t >> 4) & 15) * BN;
    const int bz  = t >> 8;
    const __bf16* A = Q  + (long)bz * (2048L * 1024);
    const __bf16* B = Kb + (long)bz * (2048L * 1024);

    f32x4 acc[4][4];
#pragma unroll
    for (int i = 0; i < 4; ++i)
#pragma unroll
      for (int j = 0; j < 4; ++j)
        acc[i][j] = (f32x4){0.f, 0.f, 0.f, 0.f};

    gemm_core(A, B, 1024, 1024, 1024, bm0, bn0, tid, wm, wn, quad, l15,
              As, Bs, acc);

    const long zc = (long)bz * (2048L * 2048);
#pragma unroll
    for (int mi = 0; mi < 4; ++mi) {
#pragma unroll
      for (int r = 0; r < 4; ++r) {
        const int gm = bm0 + wm + mi * 16 + quad * 4 + r;
        float part = 0.f;
#pragma unroll
        for (int ni = 0; ni < 4; ++ni) {
          const int gn = bn0 + wn + ni * 16 + l15;
          const __bf16 eb = (__bf16)__expf(acc[mi][ni][r] * 0.03125f);
          Sc[zc + (size_t)gm * 2048 + gn] = eb;
          part += (float)eb;  // sum the rounded values PV will actually read
        }
        part += __shfl_xor(part, 1);
        part += __shfl_xor(part, 2);
        part += __shfl_xor(part, 4);
        part += __shfl_xor(part, 8);
        if (l15 == 0)
          atomicAdd(&lsum[bz * 2048 + gm], part);
      }
    }
  }
  grid_barrier(bar, 3 * NBLK);

  // ---------------- phase 3: PV (16 x 8 x 4 batches = 512 tiles) -----------
  for (int t = blockIdx.x; t < 512; t += NBLK) {
    const int bm0 = (t & 15) * BM;
    const int bn0 = ((t >> 4) & 7) * BN;
    const int bz  = t >> 7;
    const __bf16* A = Sc + (long)bz * (2048L * 2048);
    const __bf16* B = Vt + (long)bz * (1024L * 2048);

    f32x4 acc[4][4];
#pragma unroll
    for (int i = 0; i < 4; ++i)
#pragma unroll
      for (int j = 0; j < 4; ++j)
        acc[i][j] = (f32x4){0.f, 0.f, 0.f, 0.f};

    gemm_core(A, B, 2048, 2048, 2048, bm0, bn0, tid, wm, wn, quad, l15,
              As, Bs, acc);

    const long zc = (long)bz * (2048L * 1024);
#pragma unroll
    for (int mi = 0; mi < 4; ++mi) {
#pragma unroll
      for (int r = 0; r < 4; ++r) {
        const int gm = bm0 + wm + mi * 16 + quad * 4 + r;
        const float rv = 1.0f / lsum[bz * 2048 + gm];
#pragma unroll
        for (int ni = 0; ni < 4; ++ni) {
          const int gn = bn0 + wn + ni * 16 + l15;
          out[zc + (size_t)gm * 1024 + gn] = acc[mi][ni][r] * rv;
        }
      }
    }
  }
}

extern "C" void kernel_launch(void* const* d_in, const int* in_sizes, int n_in,
                              void* d_out, int out_size, void* d_ws, size_t ws_size,
                              hipStream_t stream) {
  const float* x  = (const float*)d_in[0];
  const float* Wq = (const float*)d_in[1];
  const float* bq = (const float*)d_in[2];
  const float* Wk = (const float*)d_in[3];
  const float* bk = (const float*)d_in[4];
  const float* Wv = (const float*)d_in[5];
  const float* bv = (const float*)d_in[6];
  float* out = (float*)d_out;

  // ws layout:
  //  [0,16M)    Q    bf16 [8192][1024]
  //  [16,32M)   K    bf16 [8192][1024]
  //  [32,48M)   Vt   bf16 [4][1024][2048]
  //  [48,64M)   xb   bf16 (phase 0/1 only)
  //  [64,68M)   Wqk  bf16 [2048][1024] (phase 0/1 only)
  //  [68,70M)   Wvb  bf16 [1024][1024] (phase 0/1 only)
  //  [48,80M)   Sc   bf16 [4][2048][2048] exp-weights (aliases xb/Wqk/Wvb,
  //                   consumed by end of phase 1 — ordered by grid_barrier)
  //  [110M,+32K) lsum fp32 [8192] (zeroed by memset below)
  //  [110M+32K,+4) bar barrier counter (zeroed by memset below, every launch)
  char* ws = (char*)d_ws;
  __bf16* Q    = (__bf16*)(ws);
  __bf16* Kb   = (__bf16*)(ws + (16ull << 20));
  __bf16* Vt   = (__bf16*)(ws + (32ull << 20));
  __bf16* xb   = (__bf16*)(ws + (48ull << 20));
  __bf16* Wqk  = (__bf16*)(ws + (64ull << 20));
  __bf16* Wvb  = (__bf16*)(ws + (68ull << 20));
  __bf16* Sc   = (__bf16*)(ws + (48ull << 20));
  float*  lsum = (float*)(ws + (110ull << 20));
  unsigned* bar = (unsigned*)(ws + (110ull << 20) + 32768);

  // zero lsum + barrier counter (async memset is graph-capture safe; re-zeroed
  // on every launch/replay so the monotonic barrier targets stay valid)
  hipMemsetAsync(ws + (110ull << 20), 0, 32768 + 64, stream);

  fused_attn<<<dim3(NBLK), dim3(256), 0, stream>>>(
      x, Wq, bq, Wk, bk, Wv, bv, out,
      Q, Kb, Vt, xb, Wqk, Wvb, Sc, lsum, bar);
}

// Round 8
// 422.232 us; speedup vs baseline: 1.0128x; 1.0128x over previous
//
#include <hip/hip_runtime.h>

typedef __bf16    bf16x8 __attribute__((ext_vector_type(8)));
typedef __bf16    bf16x4 __attribute__((ext_vector_type(4)));
typedef float     f32x4  __attribute__((ext_vector_type(4)));

#define BM 128
#define BN 128
#define BK 64
#define NBLK 512   // 2 blocks/CU x 256 CU; __launch_bounds__(256,2) guarantees fit

// async global->LDS, 16B per lane. LDS dest must be wave-uniform base + lane*16.
__device__ __forceinline__ void gload_lds16(const __bf16* g, __bf16* l) {
  __builtin_amdgcn_global_load_lds(
      (const __attribute__((address_space(1))) void*)g,
      (__attribute__((address_space(3))) void*)l,
      16, 0, 0);
}

// ============================================================================
// Explicit device-scope grid barrier.
// ROUND 8 FIX: round 7 spun with atomicAdd(bar,0) — a device-scope RMW — from
// 512 blocks at s_sleep(2) (~53ns) backoff. RMWs to one line serialize at the
// coherent point (exclusive ownership per op), saturating the atomic pipe for
// the whole skew window and degrading ALL concurrent traffic (fused kernel ran
// 2.2x slower than sum-of-phases with identical MFMA-busy time: 366us vs
// 166us, MfmaUtil 13.4%). Spin is now a relaxed agent-scope atomic LOAD
// (coherent-point read, no ownership transfer, reads don't serialize) with
// s_sleep(32) (~0.85us) backoff. Arrival stays a single RMW per block.
//  release: __syncthreads (drains stores) + __threadfence, then arrive;
//  spin:    __hip_atomic_load AGENT/RELAXED — cross-XCD visible per the
//           AMDGPU memory model, no stale-L1 risk;
//  acquire: __threadfence, then __syncthreads releases the block.
// bar is memset to 0 before every launch (graph-replay safe); targets are
// monotonic (512/1024/1536) so no in-kernel reset is needed.
// ============================================================================
__device__ __forceinline__ void grid_barrier(unsigned* bar, unsigned target) {
  __syncthreads();
  if (threadIdx.x == 0) {
    __threadfence();
    atomicAdd(bar, 1u);
    while (__hip_atomic_load(bar, __ATOMIC_RELAXED,
                             __HIP_MEMORY_SCOPE_AGENT) < target)
      __builtin_amdgcn_s_sleep(32);
    __threadfence();
  }
  __syncthreads();
}

// ============================================================================
// PROVEN inner structure (round 0/5; 16x16x32, 0 bank conflicts, ~730 TF).
// Round-4 NOTE: the 32x32x16 variant of this exact layout produced 4.19M
// conflict-cycles — mechanism unresolved; do NOT switch MFMA shape without
// re-measuring conflicts.
// LDS tiles: 16B slot g' of row r holds global k-group (g' ^ (r&7)), swizzle
// applied on the GLOBAL SOURCE address (gload_lds dest must stay linear).
// ============================================================================
__device__ __forceinline__ void gemm_core(
    const __bf16* A, const __bf16* B,
    int lda, int ldb, int K, int bm0, int bn0,
    int tid, int wm, int wn, int quad, int l15,
    __bf16* As, __bf16* Bs, f32x4 (&acc)[4][4])
{
  const __bf16* Ag[4];
  const __bf16* Bg[4];
#pragma unroll
  for (int c = 0; c < 4; ++c) {
    const int r  = c * 32 + (tid >> 3);
    const int g  = (tid & 7) ^ (r & 7);
    Ag[c] = A + (size_t)(bm0 + r) * lda + g * 8;
    Bg[c] = B + (size_t)(bn0 + r) * ldb + g * 8;
  }

  for (int k0 = 0; k0 < K; k0 += BK) {
#pragma unroll
    for (int c = 0; c < 4; ++c) {
      gload_lds16(Ag[c] + k0, &As[c * 2048 + tid * 8]);
      gload_lds16(Bg[c] + k0, &Bs[c * 2048 + tid * 8]);
    }
    __syncthreads();

#pragma unroll
    for (int kk = 0; kk < 2; ++kk) {
      bf16x8 af[4], bfv[4];
#pragma unroll
      for (int i = 0; i < 4; ++i) {
        const int R = wm + i * 16 + l15;
        af[i] = *(const bf16x8*)&As[R * BK + (((kk * 4 + quad) ^ (R & 7)) * 8)];
      }
#pragma unroll
      for (int i = 0; i < 4; ++i) {
        const int R = wn + i * 16 + l15;
        bfv[i] = *(const bf16x8*)&Bs[R * BK + (((kk * 4 + quad) ^ (R & 7)) * 8)];
      }
#pragma unroll
      for (int mi = 0; mi < 4; ++mi)
#pragma unroll
        for (int ni = 0; ni < 4; ++ni)
          acc[mi][ni] = __builtin_amdgcn_mfma_f32_16x16x32_bf16(
              af[mi], bfv[ni], acc[mi][ni], 0, 0, 0);
    }
    __syncthreads();
  }
}

// ============================================================================
// Persistent fused kernel, normal launch + explicit grid barrier.
//   phase 0: fp32->bf16 cvt of x, Wq|Wk, Wv                   (grid-stride)
//   phase 1: proj — QK tiles [0,1024) + VT tiles [1024,1536)  (3 tiles/blk)
//   phase 2: scores — exp(QK^T/32)->Sc bf16 + row sums        (2 tiles/blk)
//   phase 3: PV — Sc@Vt^T * 1/lsum -> out fp32                (1 tile/blk)
// Stale-L1 audit: all cross-phase tensor reads go through global_load_lds
// (L2 path); lsum is never read before phase 3 -> no stale L1 lines possible.
// Sc aliases xb/Wqk/Wvb (consumed by end of phase 1; no __restrict__).
// ============================================================================
__global__ __launch_bounds__(256, 2)
void fused_attn(const float* __restrict__ x,  const float* __restrict__ Wq,
                const float* __restrict__ bq, const float* __restrict__ Wk,
                const float* __restrict__ bk, const float* __restrict__ Wv,
                const float* __restrict__ bv, float* out,
                __bf16* Q, __bf16* Kb, __bf16* Vt,
                __bf16* xb, __bf16* Wqk, __bf16* Wvb,
                __bf16* Sc, float* lsum, unsigned* bar)
{
  const int tid  = threadIdx.x;
  const int wave = tid >> 6;
  const int lane = tid & 63;
  const int quad = lane >> 4;
  const int l15  = lane & 15;
  const int wm   = (wave >> 1) * 64;
  const int wn   = (wave & 1) * 64;

  __shared__ __align__(16) __bf16 As[BM * BK];   // 16 KB
  __shared__ __align__(16) __bf16 Bs[BN * BK];   // 16 KB

  // ---------------- phase 0: cvt (grid-stride; lsum zeroed by host memset) --
  {
    const int g = blockIdx.x * 256 + tid;
    const int gs = NBLK * 256;
    for (int i = g; i < 2097152; i += gs) {          // x: 2^21 float4
      float4 v = ((const float4*)x)[i];
      bf16x4 o;
      o[0] = (__bf16)v.x; o[1] = (__bf16)v.y; o[2] = (__bf16)v.z; o[3] = (__bf16)v.w;
      ((bf16x4*)xb)[i] = o;
    }
    for (int i = g; i < 786432; i += gs) {           // 3 x 2^18 float4 weights
      const int mat = i >> 18;
      const int j   = i & 262143;
      const float* src = (mat == 0) ? Wq : (mat == 1) ? Wk : Wv;
      __bf16* dst = (mat == 0) ? Wqk : (mat == 1) ? (Wqk + 1048576) : Wvb;
      float4 v = ((const float4*)src)[j];
      bf16x4 o;
      o[0] = (__bf16)v.x; o[1] = (__bf16)v.y; o[2] = (__bf16)v.z; o[3] = (__bf16)v.w;
      ((bf16x4*)dst)[j] = o;
    }
  }
  grid_barrier(bar, NBLK);

  // ---------------- phase 1: proj (QK tiles 0..1023, VT tiles 1024..1535) --
  for (int t = blockIdx.x; t < 1536; t += NBLK) {
    const bool isQK = t < 1024;
    const __bf16* A;
    const __bf16* B;
    int bm0, bn0;
    if (isQK) {                       // 64 (M) x 16 (N)
      A = xb;  B = Wqk;
      bm0 = (t & 63) * BM;  bn0 = (t >> 6) * BN;
    } else {                          // 8 (M) x 64 (N)
      const int b2 = t - 1024;
      A = Wvb; B = xb;
      bm0 = (b2 & 7) * BM;  bn0 = (b2 >> 3) * BN;
    }

    f32x4 acc[4][4];
#pragma unroll
    for (int i = 0; i < 4; ++i)
#pragma unroll
      for (int j = 0; j < 4; ++j)
        acc[i][j] = (f32x4){0.f, 0.f, 0.f, 0.f};

    gemm_core(A, B, 1024, 1024, 1024, bm0, bn0, tid, wm, wn, quad, l15,
              As, Bs, acc);

    // C/D layout (verified m89/m91): row m = quad*4+r, col n = lane&15.
    if (isQK) {
#pragma unroll
      for (int mi = 0; mi < 4; ++mi) {
#pragma unroll
        for (int ni = 0; ni < 4; ++ni) {
          const int gn  = bn0 + wn + ni * 16 + l15;
          const int mat = gn >> 10;          // uniform per tile
          const int d   = gn & 1023;
          const float* bias = (mat == 0) ? bq : bk;
          __bf16* dst = (mat == 0) ? Q : Kb;
          const float bvv = bias[d];
#pragma unroll
          for (int r = 0; r < 4; ++r) {
            const int gm = bm0 + wm + mi * 16 + quad * 4 + r;
            dst[(size_t)gm * 1024 + d] = (__bf16)(acc[mi][ni][r] + bvv);
          }
        }
      }
    } else {  // VT: out Vt[b][gm][s], gn = b*2048 + s, bias bv[gm]
#pragma unroll
      for (int mi = 0; mi < 4; ++mi) {
#pragma unroll
        for (int ni = 0; ni < 4; ++ni) {
          const int gn = bn0 + wn + ni * 16 + l15;
          const int b  = gn >> 11, s = gn & 2047;
#pragma unroll
          for (int r = 0; r < 4; ++r) {
            const int gm = bm0 + wm + mi * 16 + quad * 4 + r;
            Vt[(size_t)b * (1024 * 2048) + (size_t)gm * 2048 + s] =
                (__bf16)(acc[mi][ni][r] + bv[gm]);
          }
        }
      }
    }
  }
  grid_barrier(bar, 2 * NBLK);

  // ---------------- phase 2: scores (16 x 16 x 4 batches = 1024 tiles) -----
  for (int t = blockIdx.x; t < 1024; t += NBLK) {
    const int bm0 = (t & 15) * BM;
    const int bn0 = ((t >> 4) & 15) * BN;
    const int bz  = t >> 8;
    const __bf16* A = Q  + (long)bz * (2048L * 1024);
    const __bf16* B = Kb + (long)bz * (2048L * 1024);

    f32x4 acc[4][4];
#pragma unroll
    for (int i = 0; i < 4; ++i)
#pragma unroll
      for (int j = 0; j < 4; ++j)
        acc[i][j] = (f32x4){0.f, 0.f, 0.f, 0.f};

    gemm_core(A, B, 1024, 1024, 1024, bm0, bn0, tid, wm, wn, quad, l15,
              As, Bs, acc);

    const long zc = (long)bz * (2048L * 2048);
#pragma unroll
    for (int mi = 0; mi < 4; ++mi) {
#pragma unroll
      for (int r = 0; r < 4; ++r) {
        const int gm = bm0 + wm + mi * 16 + quad * 4 + r;
        float part = 0.f;
#pragma unroll
        for (int ni = 0; ni < 4; ++ni) {
          const int gn = bn0 + wn + ni * 16 + l15;
          const __bf16 eb = (__bf16)__expf(acc[mi][ni][r] * 0.03125f);
          Sc[zc + (size_t)gm * 2048 + gn] = eb;
          part += (float)eb;  // sum the rounded values PV will actually read
        }
        part += __shfl_xor(part, 1);
        part += __shfl_xor(part, 2);
        part += __shfl_xor(part, 4);
        part += __shfl_xor(part, 8);
        if (l15 == 0)
          atomicAdd(&lsum[bz * 2048 + gm], part);
      }
    }
  }
  grid_barrier(bar, 3 * NBLK);

  // ---------------- phase 3: PV (16 x 8 x 4 batches = 512 tiles) -----------
  for (int t = blockIdx.x; t < 512; t += NBLK) {
    const int bm0 = (t & 15) * BM;
    const int bn0 = ((t >> 4) & 7) * BN;
    const int bz  = t >> 7;
    const __bf16* A = Sc + (long)bz * (2048L * 2048);
    const __bf16* B = Vt + (long)bz * (1024L * 2048);

    f32x4 acc[4][4];
#pragma unroll
    for (int i = 0; i < 4; ++i)
#pragma unroll
      for (int j = 0; j < 4; ++j)
        acc[i][j] = (f32x4){0.f, 0.f, 0.f, 0.f};

    gemm_core(A, B, 2048, 2048, 2048, bm0, bn0, tid, wm, wn, quad, l15,
              As, Bs, acc);

    const long zc = (long)bz * (2048L * 1024);
#pragma unroll
    for (int mi = 0; mi < 4; ++mi) {
#pragma unroll
      for (int r = 0; r < 4; ++r) {
        const int gm = bm0 + wm + mi * 16 + quad * 4 + r;
        const float rv = 1.0f / lsum[bz * 2048 + gm];
#pragma unroll
        for (int ni = 0; ni < 4; ++ni) {
          const int gn = bn0 + wn + ni * 16 + l15;
          out[zc + (size_t)gm * 1024 + gn] = acc[mi][ni][r] * rv;
        }
      }
    }
  }
}

extern "C" void kernel_launch(void* const* d_in, const int* in_sizes, int n_in,
                              void* d_out, int out_size, void* d_ws, size_t ws_size,
                              hipStream_t stream) {
  const float* x  = (const float*)d_in[0];
  const float* Wq = (const float*)d_in[1];
  const float* bq = (const float*)d_in[2];
  const float* Wk = (const float*)d_in[3];
  const float* bk = (const float*)d_in[4];
  const float* Wv = (const float*)d_in[5];
  const float* bv = (const float*)d_in[6];
  float* out = (float*)d_out;

  // ws layout:
  //  [0,16M)    Q    bf16 [8192][1024]
  //  [16,32M)   K    bf16 [8192][1024]
  //  [32,48M)   Vt   bf16 [4][1024][2048]
  //  [48,64M)   xb   bf16 (phase 0/1 only)
  //  [64,68M)   Wqk  bf16 [2048][1024] (phase 0/1 only)
  //  [68,70M)   Wvb  bf16 [1024][1024] (phase 0/1 only)
  //  [48,80M)   Sc   bf16 [4][2048][2048] exp-weights (aliases xb/Wqk/Wvb,
  //                   consumed by end of phase 1 — ordered by grid_barrier)
  //  [110M,+32K) lsum fp32 [8192] (zeroed by memset below)
  //  [110M+32K,+4) bar barrier counter (zeroed by memset below, every launch)
  char* ws = (char*)d_ws;
  __bf16* Q    = (__bf16*)(ws);
  __bf16* Kb   = (__bf16*)(ws + (16ull << 20));
  __bf16* Vt   = (__bf16*)(ws + (32ull << 20));
  __bf16* xb   = (__bf16*)(ws + (48ull << 20));
  __bf16* Wqk  = (__bf16*)(ws + (64ull << 20));
  __bf16* Wvb  = (__bf16*)(ws + (68ull << 20));
  __bf16* Sc   = (__bf16*)(ws + (48ull << 20));
  float*  lsum = (float*)(ws + (110ull << 20));
  unsigned* bar = (unsigned*)(ws + (110ull << 20) + 32768);

  // zero lsum + barrier counter (async memset is graph-capture safe; re-zeroed
  // on every launch/replay so the monotonic barrier targets stay valid)
  hipMemsetAsync(ws + (110ull << 20), 0, 32768 + 64, stream);

  fused_attn<<<dim3(NBLK), dim3(256), 0, stream>>>(
      x, Wq, bq, Wk, bk, Wv, bv, out,
      Q, Kb, Vt, xb, Wqk, Wvb, Sc, lsum, bar);
}

// Round 9
// 244.750 us; speedup vs baseline: 1.7472x; 1.7252x over previous
//
#include <hip/hip_runtime.h>

typedef __bf16    bf16x8 __attribute__((ext_vector_type(8)));
typedef __bf16    bf16x4 __attribute__((ext_vector_type(4)));
typedef float     f32x4  __attribute__((ext_vector_type(4)));

#define BM 128
#define BN 128
#define BK 64

// async global->LDS, 16B per lane. LDS dest must be wave-uniform base + lane*16.
__device__ __forceinline__ void gload_lds16(const __bf16* g, __bf16* l) {
  __builtin_amdgcn_global_load_lds(
      (const __attribute__((address_space(1))) void*)g,
      (__attribute__((address_space(3))) void*)l,
      16, 0, 0);
}

// ============================================================================
// SESSION LEDGER (rounds 0-8), so future edits don't re-litigate:
//  - 256^2 8-phase port (r1-r3): conflict-free but ~= 128^2 perf (47us QK A/B);
//    my port deviates from m201 (64B-row K-halves vs 128B-row M-halves) —
//    only a FAITHFUL re-port is worth trying again.
//  - 32x32x16 MFMA swap (r4): +4.19M conflict-cycles (4/read), -22% scores.
//    Mechanism unresolved; do NOT switch MFMA shape without re-measuring.
//  - proj merge QK+VT one launch (r5): VERIFIED WIN (47+24+gap -> 59us,
//    MfmaUtil 28->35.6%).
//  - persistent fusion (r6-r8): cg::sync = wrong answers; hand barrier =
//    correct but every phase uniformly 2.2x slower (same MFMA-busy, same
//    HBM bytes); RMW-spin theory FALSIFIED by relaxed-load A/B (366=366).
//    Inter-launch "gap" (~79us) is substantially harness floor. ABANDONED.
// ============================================================================

// One launch converts x (8192 blocks) + Wq/Wk/Wv (3072 blocks) to bf16.
// Block 0 additionally zero-inits the row-sum accumulator.
__global__ void cvt_all(const float* __restrict__ x, const float* __restrict__ Wq,
                        const float* __restrict__ Wk, const float* __restrict__ Wv,
                        __bf16* __restrict__ xb, __bf16* __restrict__ Wqk,
                        __bf16* __restrict__ Wvb, float* __restrict__ lsum) {
  int b = blockIdx.x;
  if (b == 0) {
    for (int j = threadIdx.x; j < 8192; j += 256) lsum[j] = 0.f;
  }
  const float* src;
  __bf16* dst;
  int i;
  if (b < 8192) {
    src = x; dst = xb; i = b * 256 + threadIdx.x;
  } else {
    b -= 8192;
    const int mat = b >> 10;
    i = (b & 1023) * 256 + threadIdx.x;
    src = (mat == 0) ? Wq : (mat == 1) ? Wk : Wv;
    dst = (mat == 0) ? Wqk : (mat == 1) ? (Wqk + 1048576) : Wvb;
  }
  float4 v = ((const float4*)src)[i];
  bf16x4 o;
  o[0] = (__bf16)v.x; o[1] = (__bf16)v.y; o[2] = (__bf16)v.z; o[3] = (__bf16)v.w;
  ((bf16x4*)dst)[i] = o;
}

// ============================================================================
// PROVEN inner structure (16x16x32, 0 bank conflicts, ~730 TF class).
// LDS tiles: 16B slot g' of row r holds global k-group (g' ^ (r&7)), swizzle
// applied on the GLOBAL SOURCE address (gload_lds dest must stay linear).
// ============================================================================
__device__ __forceinline__ void gemm_core(
    const __bf16* __restrict__ A, const __bf16* __restrict__ B,
    int lda, int ldb, int K, int bm0, int bn0,
    int tid, int wm, int wn, int quad, int l15,
    __bf16* As, __bf16* Bs, f32x4 (&acc)[4][4])
{
  const __bf16* Ag[4];
  const __bf16* Bg[4];
#pragma unroll
  for (int c = 0; c < 4; ++c) {
    const int r  = c * 32 + (tid >> 3);
    const int g  = (tid & 7) ^ (r & 7);
    Ag[c] = A + (size_t)(bm0 + r) * lda + g * 8;
    Bg[c] = B + (size_t)(bn0 + r) * ldb + g * 8;
  }

  for (int k0 = 0; k0 < K; k0 += BK) {
#pragma unroll
    for (int c = 0; c < 4; ++c) {
      gload_lds16(Ag[c] + k0, &As[c * 2048 + tid * 8]);
      gload_lds16(Bg[c] + k0, &Bs[c * 2048 + tid * 8]);
    }
    __syncthreads();

#pragma unroll
    for (int kk = 0; kk < 2; ++kk) {
      bf16x8 af[4], bfv[4];
#pragma unroll
      for (int i = 0; i < 4; ++i) {
        const int R = wm + i * 16 + l15;
        af[i] = *(const bf16x8*)&As[R * BK + (((kk * 4 + quad) ^ (R & 7)) * 8)];
      }
#pragma unroll
      for (int i = 0; i < 4; ++i) {
        const int R = wn + i * 16 + l15;
        bfv[i] = *(const bf16x8*)&Bs[R * BK + (((kk * 4 + quad) ^ (R & 7)) * 8)];
      }
#pragma unroll
      for (int mi = 0; mi < 4; ++mi)
#pragma unroll
        for (int ni = 0; ni < 4; ++ni)
          acc[mi][ni] = __builtin_amdgcn_mfma_f32_16x16x32_bf16(
              af[mi], bfv[ni], acc[mi][ni], 0, 0, 0);
    }
    __syncthreads();
  }
}

// ============================================================================
// Merged projection launch (VERIFIED round-5 win: 59.2us, MfmaUtil 35.6%).
// QK (1024 blocks) and VT (512 blocks) are independent (both read only cvt
// outputs) and share the same K=1024 gemm — one 1536-block launch removes an
// inter-kernel boundary and back-fills VT's poorly-packed tail behind QK.
//  blocks [0,1024):  QK  — xb[8192,1024] @ Wqk[2048,1024]^T -> Q,K (+bias)
//  blocks [1024,1536): VT — Wvb[1024,1024] @ xb[8192,1024]^T -> Vt (+bias[gm])
// ============================================================================
__global__ __launch_bounds__(256, 2)
void proj_qkv(const __bf16* __restrict__ xb, const __bf16* __restrict__ Wqk,
              const __bf16* __restrict__ Wvb,
              const float* __restrict__ bq, const float* __restrict__ bk,
              const float* __restrict__ bv,
              __bf16* __restrict__ Q, __bf16* __restrict__ Kb,
              __bf16* __restrict__ Vt)
{
  const int bid  = blockIdx.x;
  const int tid  = threadIdx.x;
  const int wave = tid >> 6;
  const int lane = tid & 63;
  const int quad = lane >> 4;
  const int l15  = lane & 15;
  const int wm   = (wave >> 1) * 64;
  const int wn   = (wave & 1) * 64;

  const bool isQK = bid < 1024;
  const __bf16* A;
  const __bf16* B;
  int bm0, bn0;
  if (isQK) {                       // grid 64 (M) x 16 (N)
    A = xb;  B = Wqk;
    bm0 = (bid & 63) * BM;  bn0 = (bid >> 6) * BN;
  } else {                          // grid 8 (M) x 64 (N)
    const int b2 = bid - 1024;
    A = Wvb; B = xb;
    bm0 = (b2 & 7) * BM;    bn0 = (b2 >> 3) * BN;
  }

  __shared__ __align__(16) __bf16 As[BM * BK];   // 16 KB
  __shared__ __align__(16) __bf16 Bs[BN * BK];   // 16 KB

  f32x4 acc[4][4];
#pragma unroll
  for (int i = 0; i < 4; ++i)
#pragma unroll
    for (int j = 0; j < 4; ++j)
      acc[i][j] = (f32x4){0.f, 0.f, 0.f, 0.f};

  gemm_core(A, B, 1024, 1024, 1024, bm0, bn0, tid, wm, wn, quad, l15,
            As, Bs, acc);

  // Epilogue. C/D layout (verified m89/m91): row m = quad*4+r, col n = lane&15.
  if (isQK) {
#pragma unroll
    for (int mi = 0; mi < 4; ++mi) {
#pragma unroll
      for (int ni = 0; ni < 4; ++ni) {
        const int gn  = bn0 + wn + ni * 16 + l15;
        const int mat = gn >> 10;          // uniform per tile
        const int d   = gn & 1023;
        const float* bias = (mat == 0) ? bq : bk;
        __bf16* dst = (mat == 0) ? Q : Kb;
        const float bvv = bias[d];
#pragma unroll
        for (int r = 0; r < 4; ++r) {
          const int gm = bm0 + wm + mi * 16 + quad * 4 + r;
          dst[(size_t)gm * 1024 + d] = (__bf16)(acc[mi][ni][r] + bvv);
        }
      }
    }
  } else {  // VT: out Vt[b][gm][s], gn = b*2048 + s, bias bv[gm]
#pragma unroll
    for (int mi = 0; mi < 4; ++mi) {
#pragma unroll
      for (int ni = 0; ni < 4; ++ni) {
        const int gn = bn0 + wn + ni * 16 + l15;
        const int b  = gn >> 11, s = gn & 2047;
#pragma unroll
        for (int r = 0; r < 4; ++r) {
          const int gm = bm0 + wm + mi * 16 + quad * 4 + r;
          Vt[(size_t)b * (1024 * 2048) + (size_t)gm * 2048 + s] =
              (__bf16)(acc[mi][ni][r] + bv[gm]);
        }
      }
    }
  }
}

// ============================================================================
// scores / PV kernels (proven structure).
// MODE 2: scores — e = exp(v/32) stored bf16 + per-row sums into lsum
// MODE 3: PV     — fp32 store of acc * (1/lsum[row])
// ============================================================================
template<int MODE>
__global__ __launch_bounds__(256, 2)
void gemm_bt(const __bf16* __restrict__ A, const __bf16* __restrict__ B,
             float* __restrict__ C,
             int lda, int ldb, int ldc, int K,
             long sA, long sB, long sC,
             float* __restrict__ lsum,
             __bf16* __restrict__ out0)
{
  A += (long)blockIdx.z * sA;
  B += (long)blockIdx.z * sB;

  const int tid  = threadIdx.x;
  const int wave = tid >> 6;
  const int lane = tid & 63;
  const int quad = lane >> 4;
  const int l15  = lane & 15;
  const int bm0  = blockIdx.x * BM;
  const int bn0  = blockIdx.y * BN;
  const int wm   = (wave >> 1) * 64;
  const int wn   = (wave & 1) * 64;

  __shared__ __align__(16) __bf16 As[BM * BK];   // 16 KB
  __shared__ __align__(16) __bf16 Bs[BN * BK];   // 16 KB

  f32x4 acc[4][4];
#pragma unroll
  for (int i = 0; i < 4; ++i)
#pragma unroll
    for (int j = 0; j < 4; ++j)
      acc[i][j] = (f32x4){0.f, 0.f, 0.f, 0.f};

  gemm_core(A, B, lda, ldb, K, bm0, bn0, tid, wm, wn, quad, l15,
            As, Bs, acc);

  if (MODE == 2) {
    // scores: w = exp(v/32) -> bf16; row sums into lsum via shfl+atomic.
#pragma unroll
    for (int mi = 0; mi < 4; ++mi) {
#pragma unroll
      for (int r = 0; r < 4; ++r) {
        const int gm = bm0 + wm + mi * 16 + quad * 4 + r;
        float part = 0.f;
#pragma unroll
        for (int ni = 0; ni < 4; ++ni) {
          const int gn = bn0 + wn + ni * 16 + l15;
          const __bf16 eb = (__bf16)__expf(acc[mi][ni][r] * 0.03125f);
          out0[(long)blockIdx.z * sC + (size_t)gm * ldc + gn] = eb;
          part += (float)eb;  // sum the rounded values PV will actually read
        }
        part += __shfl_xor(part, 1);
        part += __shfl_xor(part, 2);
        part += __shfl_xor(part, 4);
        part += __shfl_xor(part, 8);
        if (l15 == 0)
          atomicAdd(&lsum[blockIdx.z * 2048 + gm], part);
      }
    }
  } else {
    // PV: normalize by row sum while storing fp32.
#pragma unroll
    for (int mi = 0; mi < 4; ++mi) {
#pragma unroll
      for (int r = 0; r < 4; ++r) {
        const int gm = bm0 + wm + mi * 16 + quad * 4 + r;
        const float rv = 1.0f / lsum[blockIdx.z * 2048 + gm];
#pragma unroll
        for (int ni = 0; ni < 4; ++ni) {
          const int gn = bn0 + wn + ni * 16 + l15;
          C[(long)blockIdx.z * sC + (size_t)gm * ldc + gn] = acc[mi][ni][r] * rv;
        }
      }
    }
  }
}

extern "C" void kernel_launch(void* const* d_in, const int* in_sizes, int n_in,
                              void* d_out, int out_size, void* d_ws, size_t ws_size,
                              hipStream_t stream) {
  const float* x  = (const float*)d_in[0];
  const float* Wq = (const float*)d_in[1];
  const float* bq = (const float*)d_in[2];
  const float* Wk = (const float*)d_in[3];
  const float* bk = (const float*)d_in[4];
  const float* Wv = (const float*)d_in[5];
  const float* bv = (const float*)d_in[6];
  float* out = (float*)d_out;

  // ws layout:
  //  [0,16M)    Q    bf16 [8192][1024]
  //  [16,32M)   K    bf16 [8192][1024]
  //  [32,48M)   Vt   bf16 [4][1024][2048]
  //  [48,64M)   xb   bf16 (projection phase only)
  //  [64,68M)   Wqk  bf16 [2048][1024] (projection phase only)
  //  [68,70M)   Wvb  bf16 [1024][1024] (projection phase only)
  //  [48,80M)   Sc   bf16 [4][2048][2048] exp-weights (aliases xb/Wqk/Wvb)
  //  [110M,+32K) lsum fp32 [8192] row sums (zeroed by cvt_all block 0)
  char* ws = (char*)d_ws;
  __bf16* Q    = (__bf16*)(ws);
  __bf16* Kb   = (__bf16*)(ws + (16ull << 20));
  __bf16* Vt   = (__bf16*)(ws + (32ull << 20));
  __bf16* xb   = (__bf16*)(ws + (48ull << 20));
  __bf16* Wqk  = (__bf16*)(ws + (64ull << 20));
  __bf16* Wvb  = (__bf16*)(ws + (68ull << 20));
  __bf16* Sc   = (__bf16*)(ws + (48ull << 20));
  float*  lsum = (float*)(ws + (110ull << 20));

  dim3 blk(256);

  // fp32 -> bf16 (+ lsum zero-init), one launch
  cvt_all<<<11264, blk, 0, stream>>>(x, Wq, Wk, Wv, xb, Wqk, Wvb, lsum);

  // Merged QK + VT projection (independent outputs, shared structure)
  proj_qkv<<<1536, blk, 0, stream>>>(xb, Wqk, Wvb, bq, bk, bv, Q, Kb, Vt);

  // scores: per batch Q[2048,1024] @ K[2048,1024]^T -> bf16 exp-weights + lsum
  gemm_bt<2><<<dim3(16, 16, 4), blk, 0, stream>>>(
      Q, Kb, nullptr, 1024, 1024, 2048, 1024,
      2048L * 1024, 2048L * 1024, 2048L * 2048,
      lsum, Sc);

  // PV: per batch Sc[2048,2048](bf16) @ Vt[1024,2048]^T -> out fp32, /lsum
  gemm_bt<3><<<dim3(16, 8, 4), blk, 0, stream>>>(
      Sc, Vt, out, 2048, 2048, 1024, 2048,
      2048L * 2048, 1024L * 2048, 2048L * 1024,
      lsum, nullptr);
}

// Round 10
// 228.152 us; speedup vs baseline: 1.8743x; 1.0727x over previous
//
#include <hip/hip_runtime.h>

typedef __bf16    bf16x8 __attribute__((ext_vector_type(8)));
typedef __bf16    bf16x4 __attribute__((ext_vector_type(4)));
typedef float     f32x4  __attribute__((ext_vector_type(4)));

#define BM 128
#define BN 128
#define BK 64

// async global->LDS, 16B per lane. LDS dest must be wave-uniform base + lane*16.
__device__ __forceinline__ void gload_lds16(const __bf16* g, __bf16* l) {
  __builtin_amdgcn_global_load_lds(
      (const __attribute__((address_space(1))) void*)g,
      (__attribute__((address_space(3))) void*)l,
      16, 0, 0);
}

// ============================================================================
// SESSION LEDGER (rounds 0-9), so future edits don't re-litigate:
//  - 256^2 8-phase port (r1-r3): conflict-free but ~= 128^2 perf (47us QK A/B);
//    my port deviates from m201 (64B-row K-halves vs 128B-row M-halves) —
//    only a FAITHFUL re-port is worth trying again.
//  - 32x32x16 MFMA swap (r4): +4.19M conflict-cycles (4/read), -22% scores.
//    Mechanism unresolved; do NOT switch MFMA shape without re-measuring.
//  - proj merge QK+VT one launch (r5): VERIFIED WIN (47+24+gap -> 59us).
//  - persistent fusion (r6-r8): cg::sync = wrong answers; hand barrier =
//    correct but every phase uniformly 2.2x slower (same MFMA-busy, same
//    HBM bytes); RMW-spin theory FALSIFIED by relaxed-load A/B. Inter-launch
//    "gap" (~79us) is substantially harness floor. ABANDONED.
//  - r10: register-bucket experiment — arch 72 + acc 64 = 136 unified regs
//    sits past the 128 occupancy step (m69); shave arch to <=64 via
//    saddr+voffset staging + __launch_bounds__(256,4).
// ============================================================================

// One launch converts x (8192 blocks) + Wq/Wk/Wv (3072 blocks) to bf16.
// Block 0 additionally zero-inits the row-sum accumulator.
__global__ void cvt_all(const float* __restrict__ x, const float* __restrict__ Wq,
                        const float* __restrict__ Wk, const float* __restrict__ Wv,
                        __bf16* __restrict__ xb, __bf16* __restrict__ Wqk,
                        __bf16* __restrict__ Wvb, float* __restrict__ lsum) {
  int b = blockIdx.x;
  if (b == 0) {
    for (int j = threadIdx.x; j < 8192; j += 256) lsum[j] = 0.f;
  }
  const float* src;
  __bf16* dst;
  int i;
  if (b < 8192) {
    src = x; dst = xb; i = b * 256 + threadIdx.x;
  } else {
    b -= 8192;
    const int mat = b >> 10;
    i = (b & 1023) * 256 + threadIdx.x;
    src = (mat == 0) ? Wq : (mat == 1) ? Wk : Wv;
    dst = (mat == 0) ? Wqk : (mat == 1) ? (Wqk + 1048576) : Wvb;
  }
  float4 v = ((const float4*)src)[i];
  bf16x4 o;
  o[0] = (__bf16)v.x; o[1] = (__bf16)v.y; o[2] = (__bf16)v.z; o[3] = (__bf16)v.w;
  ((bf16x4*)dst)[i] = o;
}

// ============================================================================
// PROVEN inner structure (16x16x32, 0 bank conflicts, ~730 TF class).
// LDS tiles: 16B slot g' of row r holds global k-group (g' ^ (r&7)), swizzle
// applied on the GLOBAL SOURCE address (gload_lds dest must stay linear).
// R10 ADDRESSING: (c*32+rr)&7 == rr&7, so the swizzle group is identical for
// all 4 chunks -> staging address = UNIFORM base (A + (bm0+c*32)*lda + k0,
// SGPR) + ONE lane-varying int voffset (rr*lda + g*8). Replaces 8 x 64-bit
// VGPR pointer pairs (~16 VGPRs) with 2 VGPRs; byte-identical addresses.
// ============================================================================
__device__ __forceinline__ void gemm_core(
    const __bf16* __restrict__ A, const __bf16* __restrict__ B,
    int lda, int ldb, int K, int bm0, int bn0,
    int tid, int wm, int wn, int quad, int l15,
    __bf16* As, __bf16* Bs, f32x4 (&acc)[4][4])
{
  const int rr  = tid >> 3;                       // staging row within chunk
  const int gsl = ((tid & 7) ^ (rr & 7)) * 8;     // swizzled 16B-slot (elems)
  const int voA = rr * lda + gsl;                 // lane-varying, fits int
  const int voB = rr * ldb + gsl;

  for (int k0 = 0; k0 < K; k0 += BK) {
#pragma unroll
    for (int c = 0; c < 4; ++c) {
      gload_lds16(A + (size_t)(bm0 + c * 32) * lda + k0 + voA,
                  &As[c * 2048 + tid * 8]);
      gload_lds16(B + (size_t)(bn0 + c * 32) * ldb + k0 + voB,
                  &Bs[c * 2048 + tid * 8]);
    }
    __syncthreads();

#pragma unroll
    for (int kk = 0; kk < 2; ++kk) {
      bf16x8 af[4], bfv[4];
#pragma unroll
      for (int i = 0; i < 4; ++i) {
        const int R = wm + i * 16 + l15;
        af[i] = *(const bf16x8*)&As[R * BK + (((kk * 4 + quad) ^ (R & 7)) * 8)];
      }
#pragma unroll
      for (int i = 0; i < 4; ++i) {
        const int R = wn + i * 16 + l15;
        bfv[i] = *(const bf16x8*)&Bs[R * BK + (((kk * 4 + quad) ^ (R & 7)) * 8)];
      }
#pragma unroll
      for (int mi = 0; mi < 4; ++mi)
#pragma unroll
        for (int ni = 0; ni < 4; ++ni)
          acc[mi][ni] = __builtin_amdgcn_mfma_f32_16x16x32_bf16(
              af[mi], bfv[ni], acc[mi][ni], 0, 0, 0);
    }
    __syncthreads();
  }
}

// ============================================================================
// Merged projection launch (VERIFIED round-5 win: 59.2us, MfmaUtil 35.6%).
//  blocks [0,1024):  QK  — xb[8192,1024] @ Wqk[2048,1024]^T -> Q,K (+bias)
//  blocks [1024,1536): VT — Wvb[1024,1024] @ xb[8192,1024]^T -> Vt (+bias[gm])
// ============================================================================
__global__ __launch_bounds__(256, 4)
void proj_qkv(const __bf16* __restrict__ xb, const __bf16* __restrict__ Wqk,
              const __bf16* __restrict__ Wvb,
              const float* __restrict__ bq, const float* __restrict__ bk,
              const float* __restrict__ bv,
              __bf16* __restrict__ Q, __bf16* __restrict__ Kb,
              __bf16* __restrict__ Vt)
{
  const int bid  = blockIdx.x;
  const int tid  = threadIdx.x;
  const int wave = tid >> 6;
  const int lane = tid & 63;
  const int quad = lane >> 4;
  const int l15  = lane & 15;
  const int wm   = (wave >> 1) * 64;
  const int wn   = (wave & 1) * 64;

  const bool isQK = bid < 1024;
  const __bf16* A;
  const __bf16* B;
  int bm0, bn0;
  if (isQK) {                       // grid 64 (M) x 16 (N)
    A = xb;  B = Wqk;
    bm0 = (bid & 63) * BM;  bn0 = (bid >> 6) * BN;
  } else {                          // grid 8 (M) x 64 (N)
    const int b2 = bid - 1024;
    A = Wvb; B = xb;
    bm0 = (b2 & 7) * BM;    bn0 = (b2 >> 3) * BN;
  }

  __shared__ __align__(16) __bf16 As[BM * BK];   // 16 KB
  __shared__ __align__(16) __bf16 Bs[BN * BK];   // 16 KB

  f32x4 acc[4][4];
#pragma unroll
  for (int i = 0; i < 4; ++i)
#pragma unroll
    for (int j = 0; j < 4; ++j)
      acc[i][j] = (f32x4){0.f, 0.f, 0.f, 0.f};

  gemm_core(A, B, 1024, 1024, 1024, bm0, bn0, tid, wm, wn, quad, l15,
            As, Bs, acc);

  // Epilogue. C/D layout (verified m89/m91): row m = quad*4+r, col n = lane&15.
  if (isQK) {
#pragma unroll
    for (int mi = 0; mi < 4; ++mi) {
#pragma unroll
      for (int ni = 0; ni < 4; ++ni) {
        const int gn  = bn0 + wn + ni * 16 + l15;
        const int mat = gn >> 10;          // uniform per tile
        const int d   = gn & 1023;
        const float* bias = (mat == 0) ? bq : bk;
        __bf16* dst = (mat == 0) ? Q : Kb;
        const float bvv = bias[d];
#pragma unroll
        for (int r = 0; r < 4; ++r) {
          const int gm = bm0 + wm + mi * 16 + quad * 4 + r;
          dst[(size_t)gm * 1024 + d] = (__bf16)(acc[mi][ni][r] + bvv);
        }
      }
    }
  } else {  // VT: out Vt[b][gm][s], gn = b*2048 + s, bias bv[gm]
#pragma unroll
    for (int mi = 0; mi < 4; ++mi) {
#pragma unroll
      for (int ni = 0; ni < 4; ++ni) {
        const int gn = bn0 + wn + ni * 16 + l15;
        const int b  = gn >> 11, s = gn & 2047;
#pragma unroll
        for (int r = 0; r < 4; ++r) {
          const int gm = bm0 + wm + mi * 16 + quad * 4 + r;
          Vt[(size_t)b * (1024 * 2048) + (size_t)gm * 2048 + s] =
              (__bf16)(acc[mi][ni][r] + bv[gm]);
        }
      }
    }
  }
}

// ============================================================================
// scores / PV kernels (proven structure).
// MODE 2: scores — e = exp(v/32) stored bf16 + per-row sums into lsum
// MODE 3: PV     — fp32 store of acc * (1/lsum[row])
// ============================================================================
template<int MODE>
__global__ __launch_bounds__(256, 4)
void gemm_bt(const __bf16* __restrict__ A, const __bf16* __restrict__ B,
             float* __restrict__ C,
             int lda, int ldb, int ldc, int K,
             long sA, long sB, long sC,
             float* __restrict__ lsum,
             __bf16* __restrict__ out0)
{
  A += (long)blockIdx.z * sA;
  B += (long)blockIdx.z * sB;

  const int tid  = threadIdx.x;
  const int wave = tid >> 6;
  const int lane = tid & 63;
  const int quad = lane >> 4;
  const int l15  = lane & 15;
  const int bm0  = blockIdx.x * BM;
  const int bn0  = blockIdx.y * BN;
  const int wm   = (wave >> 1) * 64;
  const int wn   = (wave & 1) * 64;

  __shared__ __align__(16) __bf16 As[BM * BK];   // 16 KB
  __shared__ __align__(16) __bf16 Bs[BN * BK];   // 16 KB

  f32x4 acc[4][4];
#pragma unroll
  for (int i = 0; i < 4; ++i)
#pragma unroll
    for (int j = 0; j < 4; ++j)
      acc[i][j] = (f32x4){0.f, 0.f, 0.f, 0.f};

  gemm_core(A, B, lda, ldb, K, bm0, bn0, tid, wm, wn, quad, l15,
            As, Bs, acc);

  if (MODE == 2) {
    // scores: w = exp(v/32) -> bf16; row sums into lsum via shfl+atomic.
#pragma unroll
    for (int mi = 0; mi < 4; ++mi) {
#pragma unroll
      for (int r = 0; r < 4; ++r) {
        const int gm = bm0 + wm + mi * 16 + quad * 4 + r;
        float part = 0.f;
#pragma unroll
        for (int ni = 0; ni < 4; ++ni) {
          const int gn = bn0 + wn + ni * 16 + l15;
          const __bf16 eb = (__bf16)__expf(acc[mi][ni][r] * 0.03125f);
          out0[(long)blockIdx.z * sC + (size_t)gm * ldc + gn] = eb;
          part += (float)eb;  // sum the rounded values PV will actually read
        }
        part += __shfl_xor(part, 1);
        part += __shfl_xor(part, 2);
        part += __shfl_xor(part, 4);
        part += __shfl_xor(part, 8);
        if (l15 == 0)
          atomicAdd(&lsum[blockIdx.z * 2048 + gm], part);
      }
    }
  } else {
    // PV: normalize by row sum while storing fp32.
#pragma unroll
    for (int mi = 0; mi < 4; ++mi) {
#pragma unroll
      for (int r = 0; r < 4; ++r) {
        const int gm = bm0 + wm + mi * 16 + quad * 4 + r;
        const float rv = 1.0f / lsum[blockIdx.z * 2048 + gm];
#pragma unroll
        for (int ni = 0; ni < 4; ++ni) {
          const int gn = bn0 + wn + ni * 16 + l15;
          C[(long)blockIdx.z * sC + (size_t)gm * ldc + gn] = acc[mi][ni][r] * rv;
        }
      }
    }
  }
}

extern "C" void kernel_launch(void* const* d_in, const int* in_sizes, int n_in,
                              void* d_out, int out_size, void* d_ws, size_t ws_size,
                              hipStream_t stream) {
  const float* x  = (const float*)d_in[0];
  const float* Wq = (const float*)d_in[1];
  const float* bq = (const float*)d_in[2];
  const float* Wk = (const float*)d_in[3];
  const float* bk = (const float*)d_in[4];
  const float* Wv = (const float*)d_in[5];
  const float* bv = (const float*)d_in[6];
  float* out = (float*)d_out;

  // ws layout:
  //  [0,16M)    Q    bf16 [8192][1024]
  //  [16,32M)   K    bf16 [8192][1024]
  //  [32,48M)   Vt   bf16 [4][1024][2048]
  //  [48,64M)   xb   bf16 (projection phase only)
  //  [64,68M)   Wqk  bf16 [2048][1024] (projection phase only)
  //  [68,70M)   Wvb  bf16 [1024][1024] (projection phase only)
  //  [48,80M)   Sc   bf16 [4][2048][2048] exp-weights (aliases xb/Wqk/Wvb)
  //  [110M,+32K) lsum fp32 [8192] row sums (zeroed by cvt_all block 0)
  char* ws = (char*)d_ws;
  __bf16* Q    = (__bf16*)(ws);
  __bf16* Kb   = (__bf16*)(ws + (16ull << 20));
  __bf16* Vt   = (__bf16*)(ws + (32ull << 20));
  __bf16* xb   = (__bf16*)(ws + (48ull << 20));
  __bf16* Wqk  = (__bf16*)(ws + (64ull << 20));
  __bf16* Wvb  = (__bf16*)(ws + (68ull << 20));
  __bf16* Sc   = (__bf16*)(ws + (48ull << 20));
  float*  lsum = (float*)(ws + (110ull << 20));

  dim3 blk(256);

  // fp32 -> bf16 (+ lsum zero-init), one launch
  cvt_all<<<11264, blk, 0, stream>>>(x, Wq, Wk, Wv, xb, Wqk, Wvb, lsum);

  // Merged QK + VT projection (independent outputs, shared structure)
  proj_qkv<<<1536, blk, 0, stream>>>(xb, Wqk, Wvb, bq, bk, bv, Q, Kb, Vt);

  // scores: per batch Q[2048,1024] @ K[2048,1024]^T -> bf16 exp-weights + lsum
  gemm_bt<2><<<dim3(16, 16, 4), blk, 0, stream>>>(
      Q, Kb, nullptr, 1024, 1024, 2048, 1024,
      2048L * 1024, 2048L * 1024, 2048L * 2048,
      lsum, Sc);

  // PV: per batch Sc[2048,2048](bf16) @ Vt[1024,2048]^T -> out fp32, /lsum
  gemm_bt<3><<<dim3(16, 8, 4), blk, 0, stream>>>(
      Sc, Vt, out, 2048, 2048, 1024, 2048,
      2048L * 2048, 1024L * 2048, 2048L * 1024,
      lsum, nullptr);
}